// Round 6
// baseline (204.682 us; speedup 1.0000x reference)
//
#include <hip/hip_runtime.h>

// Bundle-adjustment reprojection residual.
// R5 post-mortem: gather-latency x parallelism bound (Little's law:
// ~54 outstanding reqs/CU at ~400cyc = measured 168K cycles). R6 levers:
//  - points packed to half4 (8 B rows): 4 MB table fits per-XCD 4 MiB L2
//    (nt streaming keeps it resident) -> lower latency + half the bytes
//  - poses packed to fp16 (16 B/cam = 32 KB LDS): one ds_read_b128/pose,
//    512-thread blocks get 3-4 resident blocks/CU
//  - 8 obs/thread: 8 point gathers in flight per wave
// fp16 error budget ~0.4 px vs threshold 14.56 (current absmax 2.0).

typedef float    vfloat4 __attribute__((ext_vector_type(4)));
typedef int      vint4   __attribute__((ext_vector_type(4)));
typedef _Float16 vhalf4  __attribute__((ext_vector_type(4)));
typedef _Float16 vhalf8  __attribute__((ext_vector_type(8)));

#define MAX_CAM 2000   // LDS fp16 pose table: 2000*16 = 32000 B

// ---- prep: points [N_PTS*3] f32 -> half4 rows (8 B) ----
__global__ __launch_bounds__(256) void pack_points_h(
    const float* __restrict__ src, vhalf4* __restrict__ dst, int n_pts)
{
    int i = blockIdx.x * blockDim.x + threadIdx.x;
    if (i >= n_pts) return;
    const float* s = src + 3 * i;
    vhalf4 v = {(_Float16)s[0], (_Float16)s[1], (_Float16)s[2], (_Float16)0.0f};
    dst[i] = v;
}

// ---- prep: poses [N_CAM*7] f32 -> half8 rows (16 B): t(3) q(4) pad ----
__global__ __launch_bounds__(256) void pack_poses_h(
    const float* __restrict__ src, vhalf8* __restrict__ dst, int n_cam)
{
    int i = blockIdx.x * blockDim.x + threadIdx.x;
    if (i >= n_cam) return;
    const float* s = src + 7 * i;
    vhalf8 v = {(_Float16)s[0], (_Float16)s[1], (_Float16)s[2],
                (_Float16)s[3], (_Float16)s[4], (_Float16)s[5],
                (_Float16)s[6], (_Float16)0.0f};
    dst[i] = v;
}

__global__ __launch_bounds__(512, 6) void resid_h8(
    const float*  __restrict__ obs,      // [n*2]
    const float*  __restrict__ Kmat,     // [9]
    const vhalf8* __restrict__ poses_h,  // [n_cam]
    const vhalf4* __restrict__ points_h, // [n_pts]
    const int*    __restrict__ cidx,     // [n]
    const int*    __restrict__ pidx,     // [n]
    float*        __restrict__ out,      // [n*2]
    int n, int n_cam)
{
    __shared__ vhalf8 sposes[MAX_CAM];   // 32000 B

    for (int r = threadIdx.x; r < n_cam; r += blockDim.x)
        sposes[r] = poses_h[r];
    __syncthreads();

    int t = blockIdx.x * blockDim.x + threadIdx.x;
    int base = t * 8;

    float fx = Kmat[0], cx = Kmat[2];
    float fy = Kmat[4], cy = Kmat[5];

    if (base + 8 <= n) {
        vint4 c4a = __builtin_nontemporal_load((const vint4*)(cidx + base));
        vint4 c4b = __builtin_nontemporal_load((const vint4*)(cidx + base + 4));
        vint4 p4a = __builtin_nontemporal_load((const vint4*)(pidx + base));
        vint4 p4b = __builtin_nontemporal_load((const vint4*)(pidx + base + 4));

        int cc[8] = {c4a.x, c4a.y, c4a.z, c4a.w, c4b.x, c4b.y, c4b.z, c4b.w};
        int pp[8] = {p4a.x, p4a.y, p4a.z, p4a.w, p4b.x, p4b.y, p4b.z, p4b.w};

        // all 8 point gathers in flight (8 B dwordx2 each, L2-resident table)
        vhalf4 P[8];
        #pragma unroll
        for (int k = 0; k < 8; ++k) P[k] = points_h[pp[k]];

        vfloat4 o[4];
        #pragma unroll
        for (int j = 0; j < 4; ++j)
            o[j] = __builtin_nontemporal_load((const vfloat4*)(obs + 2 * base + 4 * j));

        float res[16];
        #pragma unroll
        for (int k = 0; k < 8; ++k) {
            vhalf8 Q = sposes[cc[k]];   // one ds_read_b128
            float px = (float)P[k].x, py = (float)P[k].y, pz = (float)P[k].z;
            float tx = (float)Q[0], ty = (float)Q[1], tz = (float)Q[2];
            float qx = (float)Q[3], qy = (float)Q[4], qz = (float)Q[5], qw = (float)Q[6];

            float ux = qy * pz - qz * py;
            float uy = qz * px - qx * pz;
            float uz = qx * py - qy * px;
            float wx = ux + qw * px;
            float wy = uy + qw * py;
            float wz = uz + qw * pz;
            float ccx = qy * wz - qz * wy;
            float ccy = qz * wx - qx * wz;
            float ccz = qx * wy - qy * wx;
            float X = px + 2.0f * ccx + tx;
            float Y = py + 2.0f * ccy + ty;
            float Z = pz + 2.0f * ccz + tz;

            float invz = 1.0f / Z;
            res[2 * k]     = fx * X * invz + cx;
            res[2 * k + 1] = fy * Y * invz + cy;
        }

        #pragma unroll
        for (int j = 0; j < 4; ++j) {
            vfloat4 r = {res[4 * j]     - o[j].x, res[4 * j + 1] - o[j].y,
                         res[4 * j + 2] - o[j].z, res[4 * j + 3] - o[j].w};
            __builtin_nontemporal_store(r, (vfloat4*)(out + 2 * base + 4 * j));
        }
    } else {
        for (int i = base; i < n; ++i) {
            vhalf4 P = points_h[pidx[i]];
            vhalf8 Q = sposes[cidx[i]];
            float px = (float)P.x, py = (float)P.y, pz = (float)P.z;
            float tx = (float)Q[0], ty = (float)Q[1], tz = (float)Q[2];
            float qx = (float)Q[3], qy = (float)Q[4], qz = (float)Q[5], qw = (float)Q[6];

            float ux = qy * pz - qz * py;
            float uy = qz * px - qx * pz;
            float uz = qx * py - qy * px;
            float wx = ux + qw * px;
            float wy = uy + qw * py;
            float wz = uz + qw * pz;
            float ccx = qy * wz - qz * wy;
            float ccy = qz * wx - qx * wz;
            float ccz = qx * wy - qy * wx;
            float X = px + 2.0f * ccx + tx;
            float Y = py + 2.0f * ccy + ty;
            float Z = pz + 2.0f * ccz + tz;

            float invz = 1.0f / Z;
            out[2 * i]     = fx * X * invz + cx - obs[2 * i];
            out[2 * i + 1] = fy * Y * invz + cy - obs[2 * i + 1];
        }
    }
}

// fallback (ws too small / too many cameras): scalar fp32 path
__global__ __launch_bounds__(256) void resid_fallback(
    const float* __restrict__ obs, const float* __restrict__ Kmat,
    const float* __restrict__ poses, const float* __restrict__ points,
    const int* __restrict__ cidx, const int* __restrict__ pidx,
    float* __restrict__ out, int n)
{
    int i = blockIdx.x * blockDim.x + threadIdx.x;
    if (i >= n) return;
    const float* ps = poses + 7 * cidx[i];
    const float* pt = points + 3 * pidx[i];
    float px = pt[0], py = pt[1], pz = pt[2];
    float tx = ps[0], ty = ps[1], tz = ps[2];
    float qx = ps[3], qy = ps[4], qz = ps[5], qw = ps[6];
    float ux = qy * pz - qz * py;
    float uy = qz * px - qx * pz;
    float uz = qx * py - qy * px;
    float wx = ux + qw * px;
    float wy = uy + qw * py;
    float wz = uz + qw * pz;
    float ccx = qy * wz - qz * wy;
    float ccy = qz * wx - qx * wz;
    float ccz = qx * wy - qy * wx;
    float X = px + 2.0f * ccx + tx;
    float Y = py + 2.0f * ccy + ty;
    float Z = pz + 2.0f * ccz + tz;
    float invz = 1.0f / Z;
    out[2 * i]     = Kmat[0] * X * invz + Kmat[2] - obs[2 * i];
    out[2 * i + 1] = Kmat[4] * Y * invz + Kmat[5] - obs[2 * i + 1];
}

extern "C" void kernel_launch(void* const* d_in, const int* in_sizes, int n_in,
                              void* d_out, int out_size, void* d_ws, size_t ws_size,
                              hipStream_t stream) {
    const float* obs    = (const float*)d_in[0];
    const float* Kmat   = (const float*)d_in[1];
    const float* poses  = (const float*)d_in[2];
    const float* points = (const float*)d_in[3];
    const int*   cidx   = (const int*)d_in[4];
    const int*   pidx   = (const int*)d_in[5];
    float*       out    = (float*)d_out;

    int n     = in_sizes[4];      // N_OBS
    int n_cam = in_sizes[2] / 7;  // 2000
    int n_pts = in_sizes[3] / 3;  // 500000

    size_t pts_bytes  = (size_t)n_pts * sizeof(vhalf4);  // 4 MB
    size_t pose_bytes = (size_t)n_cam * sizeof(vhalf8);  // 32 KB

    if (ws_size < pts_bytes + pose_bytes || n_cam > MAX_CAM) {
        resid_fallback<<<(n + 255) / 256, 256, 0, stream>>>(
            obs, Kmat, poses, points, cidx, pidx, out, n);
        return;
    }

    vhalf4* points_h = (vhalf4*)d_ws;
    vhalf8* poses_h  = (vhalf8*)((char*)d_ws + pts_bytes);

    pack_points_h<<<(n_pts + 255) / 256, 256, 0, stream>>>(points, points_h, n_pts);
    pack_poses_h<<<(n_cam + 255) / 256, 256, 0, stream>>>(poses, poses_h, n_cam);

    int block = 512;
    int per_block = block * 8;
    int grid = (n + per_block - 1) / per_block;
    resid_h8<<<grid, block, 0, stream>>>(
        obs, Kmat, poses_h, points_h, cidx, pidx, out, n, n_cam);
}

// Round 7
// 163.463 us; speedup vs baseline: 1.2522x; 1.2522x over previous
//
#include <hip/hip_runtime.h>

// Bundle-adjustment reprojection residual.
// R6 post-mortem: 8-obs/thread overflowed the register budget -> compiler
// sank gathers to their uses, MLP 4->1, 40% slower. R7 = R5's proven code
// shape (4 obs/thread, batched gathers, 36 VGPR) + the orthogonal wins:
//  - fp16 point table (8 B rows, 4 MB): fits per-XCD 4 MiB L2 -> lower latency
//  - fp16 pose table (16 B rows, 32 KB LDS): ONE ds_read_b128 per pose
//  - 512-thread blocks: 32 KB LDS -> 4 blocks/CU = 32 waves (R5 was 2 blocks)

typedef float    vfloat4 __attribute__((ext_vector_type(4)));
typedef int      vint4   __attribute__((ext_vector_type(4)));
typedef _Float16 vhalf4  __attribute__((ext_vector_type(4)));
typedef _Float16 vhalf8  __attribute__((ext_vector_type(8)));

#define MAX_CAM 2000   // LDS fp16 pose table: 2000*16 = 32000 B

// ---- prep: points [N_PTS*3] f32 -> half4 rows (8 B) ----
__global__ __launch_bounds__(256) void pack_points_h(
    const float* __restrict__ src, vhalf4* __restrict__ dst, int n_pts)
{
    int i = blockIdx.x * blockDim.x + threadIdx.x;
    if (i >= n_pts) return;
    const float* s = src + 3 * i;
    vhalf4 v = {(_Float16)s[0], (_Float16)s[1], (_Float16)s[2], (_Float16)0.0f};
    dst[i] = v;
}

// ---- prep: poses [N_CAM*7] f32 -> half8 rows (16 B): t(3) q(4) pad ----
__global__ __launch_bounds__(256) void pack_poses_h(
    const float* __restrict__ src, vhalf8* __restrict__ dst, int n_cam)
{
    int i = blockIdx.x * blockDim.x + threadIdx.x;
    if (i >= n_cam) return;
    const float* s = src + 7 * i;
    vhalf8 v = {(_Float16)s[0], (_Float16)s[1], (_Float16)s[2],
                (_Float16)s[3], (_Float16)s[4], (_Float16)s[5],
                (_Float16)s[6], (_Float16)0.0f};
    dst[i] = v;
}

__global__ __launch_bounds__(512) void resid_h4(
    const float*  __restrict__ obs,      // [n*2]
    const float*  __restrict__ Kmat,     // [9]
    const vhalf8* __restrict__ poses_h,  // [n_cam]
    const vhalf4* __restrict__ points_h, // [n_pts]
    const int*    __restrict__ cidx,     // [n]
    const int*    __restrict__ pidx,     // [n]
    float*        __restrict__ out,      // [n*2]
    int n, int n_cam)
{
    __shared__ vhalf8 sposes[MAX_CAM];   // 32000 B

    for (int r = threadIdx.x; r < n_cam; r += blockDim.x)
        sposes[r] = poses_h[r];
    __syncthreads();

    int t = blockIdx.x * blockDim.x + threadIdx.x;
    int base = t * 4;

    float fx = Kmat[0], cx = Kmat[2];
    float fy = Kmat[4], cy = Kmat[5];

    if (base + 4 <= n) {
        vint4   c4  = __builtin_nontemporal_load((const vint4*)(cidx + base));
        vint4   p4  = __builtin_nontemporal_load((const vint4*)(pidx + base));
        vfloat4 o01 = __builtin_nontemporal_load((const vfloat4*)(obs + 2 * base));
        vfloat4 o23 = __builtin_nontemporal_load((const vfloat4*)(obs + 2 * base + 4));

        int cc[4] = {c4.x, c4.y, c4.z, c4.w};
        int pp[4] = {p4.x, p4.y, p4.z, p4.w};

        // 4 point gathers batched up front (same shape as R5: stays batched
        // at ~36 VGPR, keeps 4 loads in flight per thread)
        vhalf4 P[4];
        #pragma unroll
        for (int k = 0; k < 4; ++k) P[k] = points_h[pp[k]];

        // pose lookups: one ds_read_b128 each, LDS pipe
        vhalf8 Q[4];
        #pragma unroll
        for (int k = 0; k < 4; ++k) Q[k] = sposes[cc[k]];

        float res[8];
        #pragma unroll
        for (int k = 0; k < 4; ++k) {
            float px = (float)P[k].x, py = (float)P[k].y, pz = (float)P[k].z;
            float tx = (float)Q[k][0], ty = (float)Q[k][1], tz = (float)Q[k][2];
            float qx = (float)Q[k][3], qy = (float)Q[k][4],
                  qz = (float)Q[k][5], qw = (float)Q[k][6];

            float ux = qy * pz - qz * py;
            float uy = qz * px - qx * pz;
            float uz = qx * py - qy * px;
            float wx = ux + qw * px;
            float wy = uy + qw * py;
            float wz = uz + qw * pz;
            float ccx = qy * wz - qz * wy;
            float ccy = qz * wx - qx * wz;
            float ccz = qx * wy - qy * wx;
            float X = px + 2.0f * ccx + tx;
            float Y = py + 2.0f * ccy + ty;
            float Z = pz + 2.0f * ccz + tz;

            float invz = 1.0f / Z;
            res[2 * k]     = fx * X * invz + cx;
            res[2 * k + 1] = fy * Y * invz + cy;
        }

        vfloat4 r0 = {res[0] - o01.x, res[1] - o01.y, res[2] - o01.z, res[3] - o01.w};
        vfloat4 r1 = {res[4] - o23.x, res[5] - o23.y, res[6] - o23.z, res[7] - o23.w};
        __builtin_nontemporal_store(r0, (vfloat4*)(out + 2 * base));
        __builtin_nontemporal_store(r1, (vfloat4*)(out + 2 * base + 4));
    } else {
        for (int i = base; i < n; ++i) {
            vhalf4 P = points_h[pidx[i]];
            vhalf8 Q = sposes[cidx[i]];
            float px = (float)P.x, py = (float)P.y, pz = (float)P.z;
            float tx = (float)Q[0], ty = (float)Q[1], tz = (float)Q[2];
            float qx = (float)Q[3], qy = (float)Q[4], qz = (float)Q[5], qw = (float)Q[6];

            float ux = qy * pz - qz * py;
            float uy = qz * px - qx * pz;
            float uz = qx * py - qy * px;
            float wx = ux + qw * px;
            float wy = uy + qw * py;
            float wz = uz + qw * pz;
            float ccx = qy * wz - qz * wy;
            float ccy = qz * wx - qx * wz;
            float ccz = qx * wy - qy * wx;
            float X = px + 2.0f * ccx + tx;
            float Y = py + 2.0f * ccy + ty;
            float Z = pz + 2.0f * ccz + tz;

            float invz = 1.0f / Z;
            out[2 * i]     = fx * X * invz + cx - obs[2 * i];
            out[2 * i + 1] = fy * Y * invz + cy - obs[2 * i + 1];
        }
    }
}

// fallback (ws too small / too many cameras): scalar fp32 path
__global__ __launch_bounds__(256) void resid_fallback(
    const float* __restrict__ obs, const float* __restrict__ Kmat,
    const float* __restrict__ poses, const float* __restrict__ points,
    const int* __restrict__ cidx, const int* __restrict__ pidx,
    float* __restrict__ out, int n)
{
    int i = blockIdx.x * blockDim.x + threadIdx.x;
    if (i >= n) return;
    const float* ps = poses + 7 * cidx[i];
    const float* pt = points + 3 * pidx[i];
    float px = pt[0], py = pt[1], pz = pt[2];
    float tx = ps[0], ty = ps[1], tz = ps[2];
    float qx = ps[3], qy = ps[4], qz = ps[5], qw = ps[6];
    float ux = qy * pz - qz * py;
    float uy = qz * px - qx * pz;
    float uz = qx * py - qy * px;
    float wx = ux + qw * px;
    float wy = uy + qw * py;
    float wz = uz + qw * pz;
    float ccx = qy * wz - qz * wy;
    float ccy = qz * wx - qx * wz;
    float ccz = qx * wy - qy * wx;
    float X = px + 2.0f * ccx + tx;
    float Y = py + 2.0f * ccy + ty;
    float Z = pz + 2.0f * ccz + tz;
    float invz = 1.0f / Z;
    out[2 * i]     = Kmat[0] * X * invz + Kmat[2] - obs[2 * i];
    out[2 * i + 1] = Kmat[4] * Y * invz + Kmat[5] - obs[2 * i + 1];
}

extern "C" void kernel_launch(void* const* d_in, const int* in_sizes, int n_in,
                              void* d_out, int out_size, void* d_ws, size_t ws_size,
                              hipStream_t stream) {
    const float* obs    = (const float*)d_in[0];
    const float* Kmat   = (const float*)d_in[1];
    const float* poses  = (const float*)d_in[2];
    const float* points = (const float*)d_in[3];
    const int*   cidx   = (const int*)d_in[4];
    const int*   pidx   = (const int*)d_in[5];
    float*       out    = (float*)d_out;

    int n     = in_sizes[4];      // N_OBS
    int n_cam = in_sizes[2] / 7;  // 2000
    int n_pts = in_sizes[3] / 3;  // 500000

    size_t pts_bytes  = (size_t)n_pts * sizeof(vhalf4);  // 4 MB
    size_t pose_bytes = (size_t)n_cam * sizeof(vhalf8);  // 32 KB

    if (ws_size < pts_bytes + pose_bytes || n_cam > MAX_CAM) {
        resid_fallback<<<(n + 255) / 256, 256, 0, stream>>>(
            obs, Kmat, poses, points, cidx, pidx, out, n);
        return;
    }

    vhalf4* points_h = (vhalf4*)d_ws;
    vhalf8* poses_h  = (vhalf8*)((char*)d_ws + pts_bytes);

    pack_points_h<<<(n_pts + 255) / 256, 256, 0, stream>>>(points, points_h, n_pts);
    pack_poses_h<<<(n_cam + 255) / 256, 256, 0, stream>>>(poses, poses_h, n_cam);

    int block = 512;
    int per_block = block * 4;
    int grid = (n + per_block - 1) / per_block;
    resid_h4<<<grid, block, 0, stream>>>(
        obs, Kmat, poses_h, points_h, cidx, pidx, out, n, n_cam);
}

// Round 8
// 163.320 us; speedup vs baseline: 1.2533x; 1.0009x over previous
//
#include <hip/hip_runtime.h>

// Bundle-adjustment reprojection residual.
// R7 post-mortem: all rounds collapse onto ~4 cyc per L1 line-request
// (R7: 31K req/CU x 4.2 = 132K cyc). Request count is near the floor
// (1 gather/obs + streams); remaining inflation is burstiness: 1 iter
// per thread, all VMEM in one burst -> vmcnt(0) sleep, TA storm/idle.
// R8: grid-stride loop + 1-deep index prefetch. Next chunk's idx loads
// (the ~900cyc HBM leg of the dependency chain) are in flight during
// current chunk's gather+compute+store. Layout unchanged from R7:
// fp16 point table (8B rows, 4MB, L2-resident), fp16 poses in 32KB LDS,
// 4-obs gather batches (proven to stay batched at low VGPR).

typedef float    vfloat4 __attribute__((ext_vector_type(4)));
typedef int      vint4   __attribute__((ext_vector_type(4)));
typedef _Float16 vhalf4  __attribute__((ext_vector_type(4)));
typedef _Float16 vhalf8  __attribute__((ext_vector_type(8)));

#define MAX_CAM 2000   // LDS fp16 pose table: 2000*16 = 32000 B

// ---- prep: points [N_PTS*3] f32 -> half4 rows (8 B) ----
__global__ __launch_bounds__(256) void pack_points_h(
    const float* __restrict__ src, vhalf4* __restrict__ dst, int n_pts)
{
    int i = blockIdx.x * blockDim.x + threadIdx.x;
    if (i >= n_pts) return;
    const float* s = src + 3 * i;
    vhalf4 v = {(_Float16)s[0], (_Float16)s[1], (_Float16)s[2], (_Float16)0.0f};
    dst[i] = v;
}

// ---- prep: poses [N_CAM*7] f32 -> half8 rows (16 B): t(3) q(4) pad ----
__global__ __launch_bounds__(256) void pack_poses_h(
    const float* __restrict__ src, vhalf8* __restrict__ dst, int n_cam)
{
    int i = blockIdx.x * blockDim.x + threadIdx.x;
    if (i >= n_cam) return;
    const float* s = src + 7 * i;
    vhalf8 v = {(_Float16)s[0], (_Float16)s[1], (_Float16)s[2],
                (_Float16)s[3], (_Float16)s[4], (_Float16)s[5],
                (_Float16)s[6], (_Float16)0.0f};
    dst[i] = v;
}

__global__ __launch_bounds__(512) void resid_pipe(
    const float*  __restrict__ obs,      // [n*2]
    const float*  __restrict__ Kmat,     // [9]
    const vhalf8* __restrict__ poses_h,  // [n_cam]
    const vhalf4* __restrict__ points_h, // [n_pts]
    const int*    __restrict__ cidx,     // [n]
    const int*    __restrict__ pidx,     // [n]
    float*        __restrict__ out,      // [n*2]
    int n, int n_cam)
{
    __shared__ vhalf8 sposes[MAX_CAM];   // 32000 B

    for (int r = threadIdx.x; r < n_cam; r += blockDim.x)
        sposes[r] = poses_h[r];
    __syncthreads();

    float fx = Kmat[0], cx = Kmat[2];
    float fy = Kmat[4], cy = Kmat[5];

    int nchunk = n >> 2;                       // 4 obs per chunk
    int tot    = gridDim.x * blockDim.x;
    int i      = blockIdx.x * blockDim.x + threadIdx.x;

    // prologue: indices for first chunk
    vint4 c_cur = {0, 0, 0, 0}, p_cur = {0, 0, 0, 0};
    if (i < nchunk) {
        c_cur = __builtin_nontemporal_load((const vint4*)(cidx + 4 * i));
        p_cur = __builtin_nontemporal_load((const vint4*)(pidx + 4 * i));
    }

    while (i < nchunk) {
        int base  = 4 * i;
        int inext = i + tot;

        // ---- current chunk: 4 point gathers batched (L2-resident table) ----
        vhalf4 P0 = points_h[p_cur.x];
        vhalf4 P1 = points_h[p_cur.y];
        vhalf4 P2 = points_h[p_cur.z];
        vhalf4 P3 = points_h[p_cur.w];

        vfloat4 o01 = __builtin_nontemporal_load((const vfloat4*)(obs + 2 * base));
        vfloat4 o23 = __builtin_nontemporal_load((const vfloat4*)(obs + 2 * base + 4));

        // ---- prefetch next chunk's indices (hides HBM latency of idx) ----
        vint4 c_nxt = c_cur, p_nxt = p_cur;
        if (inext < nchunk) {
            c_nxt = __builtin_nontemporal_load((const vint4*)(cidx + 4 * inext));
            p_nxt = __builtin_nontemporal_load((const vint4*)(pidx + 4 * inext));
        }

        // ---- pose lookups: one ds_read_b128 each (LDS pipe) ----
        vhalf8 Q0 = sposes[c_cur.x];
        vhalf8 Q1 = sposes[c_cur.y];
        vhalf8 Q2 = sposes[c_cur.z];
        vhalf8 Q3 = sposes[c_cur.w];

        vhalf4 P[4]  = {P0, P1, P2, P3};
        vhalf8 Q[4]  = {Q0, Q1, Q2, Q3};
        float res[8];
        #pragma unroll
        for (int k = 0; k < 4; ++k) {
            float px = (float)P[k].x, py = (float)P[k].y, pz = (float)P[k].z;
            float tx = (float)Q[k][0], ty = (float)Q[k][1], tz = (float)Q[k][2];
            float qx = (float)Q[k][3], qy = (float)Q[k][4],
                  qz = (float)Q[k][5], qw = (float)Q[k][6];

            float ux = qy * pz - qz * py;
            float uy = qz * px - qx * pz;
            float uz = qx * py - qy * px;
            float wx = ux + qw * px;
            float wy = uy + qw * py;
            float wz = uz + qw * pz;
            float ccx = qy * wz - qz * wy;
            float ccy = qz * wx - qx * wz;
            float ccz = qx * wy - qy * wx;
            float X = px + 2.0f * ccx + tx;
            float Y = py + 2.0f * ccy + ty;
            float Z = pz + 2.0f * ccz + tz;

            float invz = 1.0f / Z;
            res[2 * k]     = fx * X * invz + cx;
            res[2 * k + 1] = fy * Y * invz + cy;
        }

        vfloat4 r0 = {res[0] - o01.x, res[1] - o01.y, res[2] - o01.z, res[3] - o01.w};
        vfloat4 r1 = {res[4] - o23.x, res[5] - o23.y, res[6] - o23.z, res[7] - o23.w};
        __builtin_nontemporal_store(r0, (vfloat4*)(out + 2 * base));
        __builtin_nontemporal_store(r1, (vfloat4*)(out + 2 * base + 4));

        i = inext;
        c_cur = c_nxt;
        p_cur = p_nxt;
    }

    // remainder (n % 4): single thread, scalar path
    if (blockIdx.x == 0 && threadIdx.x == 0) {
        for (int j = nchunk * 4; j < n; ++j) {
            vhalf4 P = points_h[pidx[j]];
            vhalf8 Q = sposes[cidx[j]];
            float px = (float)P.x, py = (float)P.y, pz = (float)P.z;
            float tx = (float)Q[0], ty = (float)Q[1], tz = (float)Q[2];
            float qx = (float)Q[3], qy = (float)Q[4], qz = (float)Q[5], qw = (float)Q[6];

            float ux = qy * pz - qz * py;
            float uy = qz * px - qx * pz;
            float uz = qx * py - qy * px;
            float wx = ux + qw * px;
            float wy = uy + qw * py;
            float wz = uz + qw * pz;
            float ccx = qy * wz - qz * wy;
            float ccy = qz * wx - qx * wz;
            float ccz = qx * wy - qy * wx;
            float X = px + 2.0f * ccx + tx;
            float Y = py + 2.0f * ccy + ty;
            float Z = pz + 2.0f * ccz + tz;

            float invz = 1.0f / Z;
            out[2 * j]     = fx * X * invz + cx - obs[2 * j];
            out[2 * j + 1] = fy * Y * invz + cy - obs[2 * j + 1];
        }
    }
}

// fallback (ws too small / too many cameras): scalar fp32 path
__global__ __launch_bounds__(256) void resid_fallback(
    const float* __restrict__ obs, const float* __restrict__ Kmat,
    const float* __restrict__ poses, const float* __restrict__ points,
    const int* __restrict__ cidx, const int* __restrict__ pidx,
    float* __restrict__ out, int n)
{
    int i = blockIdx.x * blockDim.x + threadIdx.x;
    if (i >= n) return;
    const float* ps = poses + 7 * cidx[i];
    const float* pt = points + 3 * pidx[i];
    float px = pt[0], py = pt[1], pz = pt[2];
    float tx = ps[0], ty = ps[1], tz = ps[2];
    float qx = ps[3], qy = ps[4], qz = ps[5], qw = ps[6];
    float ux = qy * pz - qz * py;
    float uy = qz * px - qx * pz;
    float uz = qx * py - qy * px;
    float wx = ux + qw * px;
    float wy = uy + qw * py;
    float wz = uz + qw * pz;
    float ccx = qy * wz - qz * wy;
    float ccy = qz * wx - qx * wz;
    float ccz = qx * wy - qy * wx;
    float X = px + 2.0f * ccx + tx;
    float Y = py + 2.0f * ccy + ty;
    float Z = pz + 2.0f * ccz + tz;
    float invz = 1.0f / Z;
    out[2 * i]     = Kmat[0] * X * invz + Kmat[2] - obs[2 * i];
    out[2 * i + 1] = Kmat[4] * Y * invz + Kmat[5] - obs[2 * i + 1];
}

extern "C" void kernel_launch(void* const* d_in, const int* in_sizes, int n_in,
                              void* d_out, int out_size, void* d_ws, size_t ws_size,
                              hipStream_t stream) {
    const float* obs    = (const float*)d_in[0];
    const float* Kmat   = (const float*)d_in[1];
    const float* poses  = (const float*)d_in[2];
    const float* points = (const float*)d_in[3];
    const int*   cidx   = (const int*)d_in[4];
    const int*   pidx   = (const int*)d_in[5];
    float*       out    = (float*)d_out;

    int n     = in_sizes[4];      // N_OBS
    int n_cam = in_sizes[2] / 7;  // 2000
    int n_pts = in_sizes[3] / 3;  // 500000

    size_t pts_bytes  = (size_t)n_pts * sizeof(vhalf4);  // 4 MB
    size_t pose_bytes = (size_t)n_cam * sizeof(vhalf8);  // 32 KB

    if (ws_size < pts_bytes + pose_bytes || n_cam > MAX_CAM) {
        resid_fallback<<<(n + 255) / 256, 256, 0, stream>>>(
            obs, Kmat, poses, points, cidx, pidx, out, n);
        return;
    }

    vhalf4* points_h = (vhalf4*)d_ws;
    vhalf8* poses_h  = (vhalf8*)((char*)d_ws + pts_bytes);

    pack_points_h<<<(n_pts + 255) / 256, 256, 0, stream>>>(points, points_h, n_pts);
    pack_poses_h<<<(n_cam + 255) / 256, 256, 0, stream>>>(poses, poses_h, n_cam);

    // 4 blocks/CU x 512 threads = 32 waves/CU possible; grid-stride loop
    // (~2.4 chunks/thread) so the prefetch pipeline has iterations to cover.
    int block = 512;
    int grid  = 1024;
    resid_pipe<<<grid, block, 0, stream>>>(
        obs, Kmat, poses_h, points_h, cidx, pidx, out, n, n_cam);
}